// Round 4
// baseline (814.228 us; speedup 1.0000x reference)
//
#include <hip/hip_runtime.h>
#include <cstdint>
#include <cstddef>

// Problem constants
#define NB 4
#define NC 256
#define NP 1024
#define NT 64
#define NH 8
#define ND 32
#define NF 2048            // ND*NT, joint contraction dim
#define NPT 65536          // NP*NT
#define KQV_ELEMS 67108864ull   // 32*1024*2048
#define INV_SCALE 0.022097086912079608f  // 1/sqrt(2048)

typedef unsigned short u16;
typedef __bf16 bf16x8 __attribute__((ext_vector_type(8)));
typedef short  s16x8  __attribute__((ext_vector_type(8)));
typedef short  s16x4  __attribute__((ext_vector_type(4)));
typedef float  f32x4  __attribute__((ext_vector_type(4)));

__device__ __forceinline__ u16 f2bf(float f) {
  unsigned u = __builtin_bit_cast(unsigned, f);
  u += 0x7fffu + ((u >> 16) & 1u);        // RNE
  return (u16)(u >> 16);
}
__device__ __forceinline__ float bf2f(u16 h) {
  unsigned u = ((unsigned)h) << 16;
  return __builtin_bit_cast(float, u);
}
// LDS XOR swizzle for transpose staging (byte XOR mask, bits 4..6)
__device__ __forceinline__ int swz(int row) { return ((row ^ (row >> 3)) & 7) << 4; }

#define GLOAD_LDS16(gp, lp) __builtin_amdgcn_global_load_lds( \
    (const __attribute__((address_space(1))) void*)(gp),      \
    (__attribute__((address_space(3))) void*)(lp), 16, 0, 0)

__device__ __forceinline__ f32x4 mfma16(bf16x8 a, bf16x8 b, f32x4 c) {
  return __builtin_amdgcn_mfma_f32_16x16x32_bf16(a, b, c, 0, 0, 0);
}

// ---------------------------------------------------------------------------
// Kernel 0a: W fp32 -> bf16  (3 x 256x256, row-major [o][c] preserved)
// ---------------------------------------------------------------------------
__global__ __launch_bounds__(256) void wcast_kernel(
    const float* __restrict__ Wk, const float* __restrict__ Wq,
    const float* __restrict__ Wv, u16* __restrict__ wbf)
{
  int pj = blockIdx.y;
  const float* W = (pj == 0) ? Wk : ((pj == 1) ? Wq : Wv);
  int idx = blockIdx.x * 1024 + threadIdx.x * 4;
  float4 v = *(const float4*)(W + idx);
  s16x4 pk;
  pk[0] = (short)f2bf(v.x); pk[1] = (short)f2bf(v.y);
  pk[2] = (short)f2bf(v.z); pk[3] = (short)f2bf(v.w);
  *(s16x4*)(wbf + (size_t)pj * 65536 + idx) = pk;
}

// ---------------------------------------------------------------------------
// Kernel 0b: x [b][c][pt] fp32 -> xT [(b,pt)][c] bf16  (64x64 LDS transpose)
// ---------------------------------------------------------------------------
__global__ __launch_bounds__(256, 2) void xcast_kernel(
    const float* __restrict__ x, u16* __restrict__ xT)
{
  int ptt = blockIdx.x;   // 0..1023
  int ct  = blockIdx.y;   // 0..3
  int b   = blockIdx.z;   // 0..3
  __shared__ __align__(16) u16 L[64 * 64];   // [c row][pt col], 128 B pitch
  int tid = threadIdx.x;
#pragma unroll
  for (int i = 0; i < 4; i++) {
    int cl  = i * 16 + (tid >> 4);
    int ptl = (tid & 15) * 4;
    float4 v = *(const float4*)(x + ((size_t)(b * NC + ct * 64 + cl)) * NPT +
                                ptt * 64 + ptl);
    s16x4 pk;
    pk[0] = (short)f2bf(v.x); pk[1] = (short)f2bf(v.y);
    pk[2] = (short)f2bf(v.z); pk[3] = (short)f2bf(v.w);
    *(s16x4*)((char*)L + ((cl * 128 + ptl * 2) ^ swz(cl))) = pk;
  }
  __syncthreads();
#pragma unroll
  for (int i = 0; i < 2; i++) {
    int ptl = i * 32 + (tid >> 3);
    int c8  = (tid & 7) * 8;
    s16x8 v;
#pragma unroll
    for (int j = 0; j < 8; j++) {
      int row = c8 + j;
      v[j] = (short)*(const u16*)((char*)L + ((row * 128 + ptl * 2) ^ swz(row)));
    }
    *(s16x8*)(xT + ((size_t)b * NPT + (size_t)ptt * 64 + ptl) * NC + ct * 64 + c8) = v;
  }
}

// ---------------------------------------------------------------------------
// Shared m97-style BT GEMM core (128x128 tile, BK=64, global_load_lds w16)
// C[m][n] = sum_k A[m,k]*B[n,k]   -- used by qk/av (long-K, m97 regime)
// ---------------------------------------------------------------------------
template <int KT>
__device__ __forceinline__ void gemm_core(const u16* __restrict__ A,
                                          const u16* __restrict__ Bp,
                                          u16* As, u16* Bs, f32x4 acc[4][4])
{
  const int tid = threadIdx.x, lane = tid & 63, wave = tid >> 6;
  const int wm = (wave >> 1) * 64, wn = (wave & 1) * 64;
  for (int ks = 0; ks < KT / 64; ks++) {
    const int k0 = ks * 64;
    __syncthreads();
#pragma unroll
    for (int i = 0; i < 4; i++) {
      int r0 = wave * 32 + i * 8;
      int row = r0 + (lane >> 3);
      int col = k0 + (lane & 7) * 8;
      GLOAD_LDS16(A  + (size_t)row * KT + col, &As[r0 * 64]);
      GLOAD_LDS16(Bp + (size_t)row * KT + col, &Bs[r0 * 64]);
    }
    __syncthreads();
#pragma unroll
    for (int kk = 0; kk < 2; kk++) {
      bf16x8 af[4], bfr[4];
#pragma unroll
      for (int f = 0; f < 4; f++) {
        int ra = wm + f * 16 + (lane & 15);
        af[f]  = *(const bf16x8*)((char*)As + ra * 128 + kk * 64 + (lane >> 4) * 16);
        int rb = wn + f * 16 + (lane & 15);
        bfr[f] = *(const bf16x8*)((char*)Bs + rb * 128 + kk * 64 + (lane >> 4) * 16);
      }
#pragma unroll
      for (int fm = 0; fm < 4; fm++)
#pragma unroll
        for (int fn = 0; fn < 4; fn++)
          acc[fm][fn] = mfma16(af[fm], bfr[fn], acc[fm][fn]);
    }
  }
}

// ---------------------------------------------------------------------------
// Kernel 1: fused QKV projection as pure-bf16 BT GEMM, K=256.
// 2-phase double-buffered LDS + counted vmcnt (T3/T4 minimum recipe) with the
// FULL fence set (m152 lesson / rule #18):
//   - sched_barrier(0) after STAGE issue  -> vmcnt(8) count is exact
//   - sched_barrier(0)+lgkmcnt(0) before barrier2 -> LDS reads complete
//     before any wave passes and overwrites the buffer
//   - sched_barrier(0) after each s_barrier -> nothing hoists above
// ---------------------------------------------------------------------------
__global__ __launch_bounds__(256, 2) void proj_kernel(
    const u16* __restrict__ wbf, const u16* __restrict__ xT,
    const float* __restrict__ bk, const float* __restrict__ bq,
    const float* __restrict__ bv, u16* __restrict__ kqv)
{
  // XCD-grouped decode: 6 workgroups (2 m-tiles x 3 proj) share a pt-tile
  int d0 = blockIdx.x;               // 0..3071
  int b  = blockIdx.y;
  int xcd = d0 & 7, r = d0 >> 3;     // r: 0..383
  int j = r % 6, tch = r / 6;
  int ptile = tch * 8 + xcd;         // 0..511
  int pj = j >> 1, mt = j & 1;
  const float* bias = (pj == 0) ? bk : ((pj == 1) ? bq : bv);
  u16* outb = kqv + (size_t)pj * KQV_ELEMS;

  const int m0 = mt * 128;           // o offset
  const int n0 = ptile * 128;        // pt offset

  const u16* A  = wbf + (size_t)pj * 65536 + (size_t)m0 * NC;
  const u16* Bp = xT + ((size_t)b * NPT + (size_t)n0) * NC;

  __shared__ __align__(16) u16 As[2][128 * 64];
  __shared__ __align__(16) u16 Bs[2][128 * 64];

  const int tid  = threadIdx.x;
  const int lane = tid & 63;
  const int wave = tid >> 6;
  const int wm = (wave >> 1) * 64, wn = (wave & 1) * 64;

  f32x4 acc[4][4];
#pragma unroll
  for (int a = 0; a < 4; a++)
#pragma unroll
    for (int c = 0; c < 4; c++) acc[a][c] = (f32x4){0.f, 0.f, 0.f, 0.f};

  // 8 gload_lds per thread per tile (4 A + 4 B)
  auto STAGE = [&](int pb, int k0) {
#pragma unroll
    for (int i = 0; i < 4; i++) {
      int r0 = wave * 32 + i * 8;
      int row = r0 + (lane >> 3);
      int col = k0 + (lane & 7) * 8;
      GLOAD_LDS16(A  + (size_t)row * NC + col, &As[pb][r0 * 64]);
      GLOAD_LDS16(Bp + (size_t)row * NC + col, &Bs[pb][r0 * 64]);
    }
  };

  STAGE(0, 0);
  __builtin_amdgcn_sched_barrier(0);
#pragma unroll
  for (int ks = 0; ks < 4; ks++) {
    if (ks < 3) {
      STAGE((ks + 1) & 1, (ks + 1) * 64);
      __builtin_amdgcn_sched_barrier(0);  // all 8 next-tile loads issued above
      asm volatile("s_waitcnt vmcnt(8)" ::: "memory");  // current tile landed
    } else {
      asm volatile("s_waitcnt vmcnt(0)" ::: "memory");
    }
    __builtin_amdgcn_s_barrier();        // barrier1: tile visible to all waves
    __builtin_amdgcn_sched_barrier(0);   // pin LDS reads below (rule #18)
    const u16* Asb = As[ks & 1];
    const u16* Bsb = Bs[ks & 1];
#pragma unroll
    for (int kk = 0; kk < 2; kk++) {
      bf16x8 af[4], bfr[4];
#pragma unroll
      for (int f = 0; f < 4; f++) {
        int ra = wm + f * 16 + (lane & 15);
        af[f]  = *(const bf16x8*)((char*)Asb + ra * 128 + kk * 64 + (lane >> 4) * 16);
        int rb = wn + f * 16 + (lane & 15);
        bfr[f] = *(const bf16x8*)((char*)Bsb + rb * 128 + kk * 64 + (lane >> 4) * 16);
      }
#pragma unroll
      for (int fm = 0; fm < 4; fm++)
#pragma unroll
        for (int fn = 0; fn < 4; fn++)
          acc[fm][fn] = mfma16(af[fm], bfr[fn], acc[fm][fn]);
    }
    __builtin_amdgcn_sched_barrier(0);   // MFMAs + ds_reads stay above
    asm volatile("s_waitcnt lgkmcnt(0)" ::: "memory");  // LDS reads complete
    __builtin_amdgcn_s_barrier();        // barrier2: safe to overwrite buffer
    __builtin_amdgcn_sched_barrier(0);   // next-iter STAGE stays below
  }

  // ---- epilogue: + bias, bf16, scatter to [bh][p][d*64+t]
#pragma unroll
  for (int fm = 0; fm < 4; fm++) {
#pragma unroll
    for (int jj = 0; jj < 4; jj++) {
      int m = wm + fm * 16 + (lane >> 4) * 4 + jj;
      int o = m0 + m;
      float bsv = bias[o];
      int hh = o >> 5, dd = o & 31;
#pragma unroll
      for (int fn = 0; fn < 4; fn++) {
        int n = n0 + wn + fn * 16 + (lane & 15);
        int p = n >> 6, t = n & 63;
        outb[((size_t)(b * NH + hh) * NP + p) * NF + dd * 64 + t] =
            f2bf(acc[fm][fn][jj] + bsv);
      }
    }
  }
}

// ---------------------------------------------------------------------------
// Kernel 2: V transpose  [bh][p][f] -> [bh][f][p]   (64x64 tiles, swizzled LDS)
// ---------------------------------------------------------------------------
__global__ __launch_bounds__(256, 2) void transpose_kernel(
    const u16* __restrict__ in, u16* __restrict__ outp)
{
  int ft = blockIdx.x;   // 0..31  f-tiles
  int pt = blockIdx.y;   // 0..15  p-tiles
  int slab = blockIdx.z; // 0..31  bh
  __shared__ __align__(16) u16 L[64 * 64];
  int t = threadIdx.x;
  const u16* ip = in + (size_t)slab * NP * NF;
#pragma unroll
  for (int i = 0; i < 2; i++) {
    int pl = i * 32 + (t >> 3);
    int c8 = (t & 7) * 8;
    s16x8 v = *(const s16x8*)(ip + (size_t)(pt * 64 + pl) * NF + ft * 64 + c8);
    *(s16x8*)((char*)L + ((pl * 128 + c8 * 2) ^ swz(pl))) = v;
  }
  __syncthreads();
  u16* op = outp + (size_t)slab * NP * NF;
#pragma unroll
  for (int i = 0; i < 2; i++) {
    int fl = i * 32 + (t >> 3);
    int p8 = (t & 7) * 8;
    s16x8 v;
#pragma unroll
    for (int j2 = 0; j2 < 8; j2++) {
      int row = p8 + j2;
      v[j2] = (short)*(const u16*)((char*)L + ((row * 128 + fl * 2) ^ swz(row)));
    }
    *(s16x8*)(op + (size_t)(ft * 64 + fl) * NP + pt * 64 + p8) = v;
  }
}

// S'[q][p] = (sum_f Q[q,f] K[p,f]) * INV_SCALE   (operands swapped: A=Q, B=K)
__global__ __launch_bounds__(256, 2) void qk_kernel(
    const u16* __restrict__ kb, const u16* __restrict__ qb, u16* __restrict__ S)
{
  int bid = blockIdx.x;                 // 2048, XCD-swizzled: slab-per-XCD
  int xcd = bid & 7, r = bid >> 3;
  int bh = xcd * 4 + (r >> 6);
  int idx = r & 63;
  int mt = idx >> 3, nt = idx & 7;

  const u16* A  = qb + (size_t)bh * NP * NF + (size_t)mt * 128 * NF;
  const u16* Bp = kb + (size_t)bh * NP * NF + (size_t)nt * 128 * NF;

  __shared__ __align__(16) u16 As[128 * 64];
  __shared__ __align__(16) u16 Bs[128 * 64];

  f32x4 acc[4][4];
#pragma unroll
  for (int a = 0; a < 4; a++)
#pragma unroll
    for (int c = 0; c < 4; c++) acc[a][c] = (f32x4){0.f, 0.f, 0.f, 0.f};

  gemm_core<NF>(A, Bp, As, Bs, acc);

  const int lane = threadIdx.x & 63, wave = threadIdx.x >> 6;
  const int wm = (wave >> 1) * 64, wn = (wave & 1) * 64;
  u16* Sp = S + (size_t)bh * NP * NP;
#pragma unroll
  for (int fm = 0; fm < 4; fm++)
#pragma unroll
    for (int jj = 0; jj < 4; jj++) {
      int m = mt * 128 + wm + fm * 16 + (lane >> 4) * 4 + jj;   // q
#pragma unroll
      for (int fn = 0; fn < 4; fn++) {
        int n = nt * 128 + wn + fn * 16 + (lane & 15);          // p
        Sp[(size_t)m * NP + n] = f2bf(acc[fm][fn][jj] * INV_SCALE);
      }
    }
}

// Column softmax over q (rows of S'[q][p]); coalesced along p. 4-way q-split.
__global__ __launch_bounds__(256, 2) void softmax_kernel(
    const u16* __restrict__ S, u16* __restrict__ A)
{
  int cb = blockIdx.x;        // 16 blocks of 64 columns
  int bh = blockIdx.y;
  int tid = threadIdx.x;
  int c  = tid & 63;
  int qs = tid >> 6;          // 0..3
  int col = cb * 64 + c;
  const u16* Sp = S + (size_t)bh * NP * NP + col;
  float m = -1e30f, l = 0.f;
  for (int q = qs * 256; q < qs * 256 + 256; q++) {
    float v = bf2f(Sp[(size_t)q * NP]);
    float mn = fmaxf(m, v);
    l = l * __expf(m - mn) + __expf(v - mn);
    m = mn;
  }
  __shared__ float ms[4][64], ls[4][64];
  ms[qs][c] = m; ls[qs][c] = l;
  __syncthreads();
  float M = fmaxf(fmaxf(ms[0][c], ms[1][c]), fmaxf(ms[2][c], ms[3][c]));
  float L = ls[0][c] * __expf(ms[0][c] - M) + ls[1][c] * __expf(ms[1][c] - M) +
            ls[2][c] * __expf(ms[2][c] - M) + ls[3][c] * __expf(ms[3][c] - M);
  float inv = 1.f / L;
  u16* Ap = A + (size_t)bh * NP * NP + col;
  for (int q = qs * 256; q < qs * 256 + 256; q++) {
    float v = bf2f(Sp[(size_t)q * NP]);
    Ap[(size_t)q * NP] = f2bf(__expf(v - M) * inv);
  }
}

// Out[q][f] = sum_p A'[q,p] * Vt[f,p];  write fp32 out[b][h*32+d][q][t]
__global__ __launch_bounds__(256, 2) void av_kernel(
    const u16* __restrict__ Ab, const u16* __restrict__ Vt, float* __restrict__ out)
{
  int bid = blockIdx.x;                 // 4096, XCD-swizzled
  int xcd = bid & 7, r = bid >> 3;
  int bh = xcd * 4 + (r >> 7);
  int idx = r & 127;
  int mt = idx >> 4, nt = idx & 15;

  const u16* A  = Ab + (size_t)bh * NP * NP + (size_t)mt * 128 * NP;
  const u16* Bp = Vt + (size_t)bh * NF * NP + (size_t)nt * 128 * NP;

  __shared__ __align__(16) u16 As[128 * 64];
  __shared__ __align__(16) u16 Bs[128 * 64];

  f32x4 acc[4][4];
#pragma unroll
  for (int a = 0; a < 4; a++)
#pragma unroll
    for (int c = 0; c < 4; c++) acc[a][c] = (f32x4){0.f, 0.f, 0.f, 0.f};

  gemm_core<NP>(A, Bp, As, Bs, acc);

  const int lane = threadIdx.x & 63, wave = threadIdx.x >> 6;
  const int wm = (wave >> 1) * 64, wn = (wave & 1) * 64;
  int b = bh >> 3, h = bh & 7;
#pragma unroll
  for (int fm = 0; fm < 4; fm++)
#pragma unroll
    for (int jj = 0; jj < 4; jj++) {
      int m = mt * 128 + wm + fm * 16 + (lane >> 4) * 4 + jj;   // q
#pragma unroll
      for (int fn = 0; fn < 4; fn++) {
        int n = nt * 128 + wn + fn * 16 + (lane & 15);          // f
        int dd = n >> 6, t = n & 63;
        out[((size_t)(b * NC + h * ND + dd) * NP + m) * NT + t] = acc[fm][fn][jj];
      }
    }
}

// ---------------------------------------------------------------------------
extern "C" void kernel_launch(void* const* d_in, const int* in_sizes, int n_in,
                              void* d_out, int out_size, void* d_ws, size_t ws_size,
                              hipStream_t stream)
{
  if (ws_size < 4ull * KQV_ELEMS * sizeof(u16)) return;  // need 537 MB scratch

  const float* x  = (const float*)d_in[0];
  const float* Wk = (const float*)d_in[1];
  const float* bk = (const float*)d_in[2];
  const float* Wq = (const float*)d_in[3];
  const float* bq = (const float*)d_in[4];
  const float* Wv = (const float*)d_in[5];
  const float* bv = (const float*)d_in[6];

  u16* kb = (u16*)d_ws;                    // [bh][p][f]
  u16* qb = kb + KQV_ELEMS;                // [bh][p][f]
  u16* vb = kb + 2 * KQV_ELEMS;            // [bh][p][f]
  u16* vt = kb + 3 * KQV_ELEMS;            // [bh][f][p]

  // d_out head doubles as staging: xT (134 MB) + wbf (0.4 MB) + S (67 MB).
  // All dead before av_kernel rewrites d_out in full.
  u16* xT  = (u16*)d_out;                  // [(b,pt)][c]  67,108,864 u16
  u16* wbf = xT + KQV_ELEMS;               // 3 x 256 x 256
  u16* Sb  = xT + KQV_ELEMS + 262144;      // S'[bh][q][p] 33,554,432 u16
  u16* Ab  = kb;                           // attn A'[bh][q][p], aliases kb

  wcast_kernel<<<dim3(64, 3), 256, 0, stream>>>(Wk, Wq, Wv, wbf);
  xcast_kernel<<<dim3(1024, 4, 4), 256, 0, stream>>>(x, xT);
  proj_kernel<<<dim3(3072, 4), 256, 0, stream>>>(wbf, xT, bk, bq, bv, kb);
  transpose_kernel<<<dim3(32, 16, 32), 256, 0, stream>>>(vb, vt);
  qk_kernel<<<dim3(2048), 256, 0, stream>>>(kb, qb, Sb);
  softmax_kernel<<<dim3(16, 32), 256, 0, stream>>>(Sb, Ab);
  av_kernel<<<dim3(4096), 256, 0, stream>>>(Ab, vt, (float*)d_out);
}

// Round 5
// 718.969 us; speedup vs baseline: 1.1325x; 1.1325x over previous
//
#include <hip/hip_runtime.h>
#include <cstdint>
#include <cstddef>

// Problem constants
#define NB 4
#define NC 256
#define NP 1024
#define NT 64
#define NH 8
#define ND 32
#define NF 2048            // ND*NT, joint contraction dim
#define NPT 65536          // NP*NT
#define KQV_ELEMS 67108864ull   // 32*1024*2048
#define INV_SCALE 0.022097086912079608f  // 1/sqrt(2048)

typedef unsigned short u16;
typedef __bf16 bf16x8 __attribute__((ext_vector_type(8)));
typedef short  s16x8  __attribute__((ext_vector_type(8)));
typedef short  s16x4  __attribute__((ext_vector_type(4)));
typedef float  f32x4  __attribute__((ext_vector_type(4)));

__device__ __forceinline__ u16 f2bf(float f) {
  unsigned u = __builtin_bit_cast(unsigned, f);
  u += 0x7fffu + ((u >> 16) & 1u);        // RNE
  return (u16)(u >> 16);
}
__device__ __forceinline__ float bf2f(u16 h) {
  unsigned u = ((unsigned)h) << 16;
  return __builtin_bit_cast(float, u);
}
// LDS XOR swizzle for transpose staging (byte XOR mask, bits 4..6)
__device__ __forceinline__ int swz(int row) { return ((row ^ (row >> 3)) & 7) << 4; }

#define GLOAD_LDS16(gp, lp) __builtin_amdgcn_global_load_lds( \
    (const __attribute__((address_space(1))) void*)(gp),      \
    (__attribute__((address_space(3))) void*)(lp), 16, 0, 0)

__device__ __forceinline__ f32x4 mfma16(bf16x8 a, bf16x8 b, f32x4 c) {
  return __builtin_amdgcn_mfma_f32_16x16x32_bf16(a, b, c, 0, 0, 0);
}

// ---------------------------------------------------------------------------
// Kernel 0a: W fp32 -> bf16  (3 x 256x256, row-major [o][c] preserved)
// ---------------------------------------------------------------------------
__global__ __launch_bounds__(256) void wcast_kernel(
    const float* __restrict__ Wk, const float* __restrict__ Wq,
    const float* __restrict__ Wv, u16* __restrict__ wbf)
{
  int pj = blockIdx.y;
  const float* W = (pj == 0) ? Wk : ((pj == 1) ? Wq : Wv);
  int idx = blockIdx.x * 1024 + threadIdx.x * 4;
  float4 v = *(const float4*)(W + idx);
  s16x4 pk;
  pk[0] = (short)f2bf(v.x); pk[1] = (short)f2bf(v.y);
  pk[2] = (short)f2bf(v.z); pk[3] = (short)f2bf(v.w);
  *(s16x4*)(wbf + (size_t)pj * 65536 + idx) = pk;
}

// ---------------------------------------------------------------------------
// Kernel 0b: x [b][c][pt] fp32 -> xT [(b,pt)][c] bf16  (64x64 LDS transpose)
// ---------------------------------------------------------------------------
__global__ __launch_bounds__(256, 2) void xcast_kernel(
    const float* __restrict__ x, u16* __restrict__ xT)
{
  int ptt = blockIdx.x;   // 0..1023
  int ct  = blockIdx.y;   // 0..3
  int b   = blockIdx.z;   // 0..3
  __shared__ __align__(16) u16 L[64 * 64];   // [c row][pt col], 128 B pitch
  int tid = threadIdx.x;
#pragma unroll
  for (int i = 0; i < 4; i++) {
    int cl  = i * 16 + (tid >> 4);
    int ptl = (tid & 15) * 4;
    float4 v = *(const float4*)(x + ((size_t)(b * NC + ct * 64 + cl)) * NPT +
                                ptt * 64 + ptl);
    s16x4 pk;
    pk[0] = (short)f2bf(v.x); pk[1] = (short)f2bf(v.y);
    pk[2] = (short)f2bf(v.z); pk[3] = (short)f2bf(v.w);
    *(s16x4*)((char*)L + ((cl * 128 + ptl * 2) ^ swz(cl))) = pk;
  }
  __syncthreads();
#pragma unroll
  for (int i = 0; i < 2; i++) {
    int ptl = i * 32 + (tid >> 3);
    int c8  = (tid & 7) * 8;
    s16x8 v;
#pragma unroll
    for (int j = 0; j < 8; j++) {
      int row = c8 + j;
      v[j] = (short)*(const u16*)((char*)L + ((row * 128 + ptl * 2) ^ swz(row)));
    }
    *(s16x8*)(xT + ((size_t)b * NPT + (size_t)ptt * 64 + ptl) * NC + ct * 64 + c8) = v;
  }
}

// ---------------------------------------------------------------------------
// m97-style BT GEMM core (128x128 tile, BK=64) -- used by proj only (K=256)
// ---------------------------------------------------------------------------
template <int KT>
__device__ __forceinline__ void gemm_core(const u16* __restrict__ A,
                                          const u16* __restrict__ Bp,
                                          u16* As, u16* Bs, f32x4 acc[4][4])
{
  const int tid = threadIdx.x, lane = tid & 63, wave = tid >> 6;
  const int wm = (wave >> 1) * 64, wn = (wave & 1) * 64;
  for (int ks = 0; ks < KT / 64; ks++) {
    const int k0 = ks * 64;
    __syncthreads();
#pragma unroll
    for (int i = 0; i < 4; i++) {
      int r0 = wave * 32 + i * 8;
      int row = r0 + (lane >> 3);
      int col = k0 + (lane & 7) * 8;
      GLOAD_LDS16(A  + (size_t)row * KT + col, &As[r0 * 64]);
      GLOAD_LDS16(Bp + (size_t)row * KT + col, &Bs[r0 * 64]);
    }
    __syncthreads();
#pragma unroll
    for (int kk = 0; kk < 2; kk++) {
      bf16x8 af[4], bfr[4];
#pragma unroll
      for (int f = 0; f < 4; f++) {
        int ra = wm + f * 16 + (lane & 15);
        af[f]  = *(const bf16x8*)((char*)As + ra * 128 + kk * 64 + (lane >> 4) * 16);
        int rb = wn + f * 16 + (lane & 15);
        bfr[f] = *(const bf16x8*)((char*)Bs + rb * 128 + kk * 64 + (lane >> 4) * 16);
      }
#pragma unroll
      for (int fm = 0; fm < 4; fm++)
#pragma unroll
        for (int fn = 0; fn < 4; fn++)
          acc[fm][fn] = mfma16(af[fm], bfr[fn], acc[fm][fn]);
    }
  }
}

// ---------------------------------------------------------------------------
// Kernel 1: fused QKV projection (R2 structure: single-buffer, 32 KB LDS)
// ---------------------------------------------------------------------------
__global__ __launch_bounds__(256, 2) void proj_kernel(
    const u16* __restrict__ wbf, const u16* __restrict__ xT,
    const float* __restrict__ bk, const float* __restrict__ bq,
    const float* __restrict__ bv, u16* __restrict__ kqv)
{
  int d0 = blockIdx.x;               // 0..3071
  int b  = blockIdx.y;
  int xcd = d0 & 7, r = d0 >> 3;     // r: 0..383
  int j = r % 6, tch = r / 6;
  int ptile = tch * 8 + xcd;         // 0..511
  int pj = j >> 1, mt = j & 1;
  const float* bias = (pj == 0) ? bk : ((pj == 1) ? bq : bv);
  u16* outb = kqv + (size_t)pj * KQV_ELEMS;

  const int m0 = mt * 128;           // o offset
  const int n0 = ptile * 128;        // pt offset

  const u16* A  = wbf + (size_t)pj * 65536 + (size_t)m0 * NC;
  const u16* Bp = xT + ((size_t)b * NPT + (size_t)n0) * NC;

  __shared__ __align__(16) u16 As[128 * 64];
  __shared__ __align__(16) u16 Bs[128 * 64];

  f32x4 acc[4][4];
#pragma unroll
  for (int a = 0; a < 4; a++)
#pragma unroll
    for (int c = 0; c < 4; c++) acc[a][c] = (f32x4){0.f, 0.f, 0.f, 0.f};

  gemm_core<NC>(A, Bp, As, Bs, acc);

  const int lane = threadIdx.x & 63, wave = threadIdx.x >> 6;
  const int wm = (wave >> 1) * 64, wn = (wave & 1) * 64;
#pragma unroll
  for (int fm = 0; fm < 4; fm++) {
#pragma unroll
    for (int jj = 0; jj < 4; jj++) {
      int m = wm + fm * 16 + (lane >> 4) * 4 + jj;
      int o = m0 + m;
      float bsv = bias[o];
      int hh = o >> 5, dd = o & 31;
#pragma unroll
      for (int fn = 0; fn < 4; fn++) {
        int n = n0 + wn + fn * 16 + (lane & 15);
        int p = n >> 6, t = n & 63;
        outb[((size_t)(b * NH + hh) * NP + p) * NF + dd * 64 + t] =
            f2bf(acc[fm][fn][jj] + bsv);
      }
    }
  }
}

// ---------------------------------------------------------------------------
// Kernel 2: V transpose  [bh][p][f] -> [bh][f][p]
// ---------------------------------------------------------------------------
__global__ __launch_bounds__(256, 2) void transpose_kernel(
    const u16* __restrict__ in, u16* __restrict__ outp)
{
  int ft = blockIdx.x;   // 0..31  f-tiles
  int pt = blockIdx.y;   // 0..15  p-tiles
  int slab = blockIdx.z; // 0..31  bh
  __shared__ __align__(16) u16 L[64 * 64];
  int t = threadIdx.x;
  const u16* ip = in + (size_t)slab * NP * NF;
#pragma unroll
  for (int i = 0; i < 2; i++) {
    int pl = i * 32 + (t >> 3);
    int c8 = (t & 7) * 8;
    s16x8 v = *(const s16x8*)(ip + (size_t)(pt * 64 + pl) * NF + ft * 64 + c8);
    *(s16x8*)((char*)L + ((pl * 128 + c8 * 2) ^ swz(pl))) = v;
  }
  __syncthreads();
  u16* op = outp + (size_t)slab * NP * NF;
#pragma unroll
  for (int i = 0; i < 2; i++) {
    int fl = i * 32 + (t >> 3);
    int p8 = (t & 7) * 8;
    s16x8 v;
#pragma unroll
    for (int j2 = 0; j2 < 8; j2++) {
      int row = p8 + j2;
      v[j2] = (short)*(const u16*)((char*)L + ((row * 128 + fl * 2) ^ swz(row)));
    }
    *(s16x8*)(op + (size_t)(ft * 64 + fl) * NP + pt * 64 + p8) = v;
  }
}

// ---------------------------------------------------------------------------
// 256x256 deep-pipelined BT GEMM core (BK=32, 4 LDS buffers, 512 threads,
// 8 waves 2Mx4N). Race-free by construction: buffer b is staged only while
// computing b-3; every phase drains its ds_reads (lgkmcnt(0)) before its end
// barrier, so no wave can overwrite a buffer another wave still reads.
// Counted vmcnt(8) steady state (2 tiles x 4 loads in flight), tail 8->4->0.
// T2 swizzle: involution off ^= ((off>>6)&3)<<4 (pre-swizzled global source,
// swizzled ds_read). T5 setprio around each 16-MFMA cluster.
// ---------------------------------------------------------------------------
#define STG1(TT, I, OP) do {                                                   \
    const u16* gp_ = (OP ? Bg : Ag) + (size_t)grow[I] * KT + (TT) * 32 + gcol[I]; \
    GLOAD_LDS16(gp_, L + ((((TT) & 3) * 32768 + (OP) * 16384 +                 \
                           ((I) & 1 ? W1 : W0)) >> 1));                        \
  } while (0)

#define FENCE() do {                                                           \
    asm volatile("" ::: "memory");                                             \
    __builtin_amdgcn_sched_barrier(0);                                         \
  } while (0)

#define KBODY(J, WAITASM, DOSTG) do {                                          \
    const int bufb_ = ((J) & 3) * 32768;                                       \
    bf16x8 a_[4], b_[4];                                                       \
    _Pragma("unroll")                                                          \
    for (int mf = 0; mf < 4; mf++)                                             \
      a_[mf] = *(const bf16x8*)((const char*)L + bufb_ + baseA + mf * 1024);   \
    _Pragma("unroll")                                                          \
    for (int nf = 0; nf < 4; nf++)                                             \
      b_[nf] = *(const bf16x8*)((const char*)L + bufb_ + baseB + nf * 1024);   \
    if (DOSTG) { STG1((J) + 3, 0, 0); STG1((J) + 3, 1, 0); }                   \
    __builtin_amdgcn_s_barrier();                                              \
    asm volatile("s_waitcnt lgkmcnt(0)" ::: "memory");                         \
    __builtin_amdgcn_sched_barrier(0);                                         \
    __builtin_amdgcn_s_setprio(1);                                             \
    _Pragma("unroll")                                                          \
    for (int mf = 0; mf < 4; mf++)                                             \
      _Pragma("unroll")                                                        \
      for (int nf = 0; nf < 4; nf++)                                           \
        acc[mf][nf] = mfma16(a_[mf], b_[nf], acc[mf][nf]);                     \
    __builtin_amdgcn_s_setprio(0);                                             \
    __builtin_amdgcn_sched_barrier(0);                                         \
    __builtin_amdgcn_s_barrier();                                              \
    FENCE();                                                                   \
    bf16x8 a2_[4];                                                             \
    _Pragma("unroll")                                                          \
    for (int mf = 0; mf < 4; mf++)                                             \
      a2_[mf] = *(const bf16x8*)((const char*)L + bufb_ + baseA +              \
                                 (4 + mf) * 1024);                             \
    if (DOSTG) { STG1((J) + 3, 2, 1); STG1((J) + 3, 3, 1); }                   \
    __builtin_amdgcn_s_barrier();                                              \
    asm volatile("s_waitcnt lgkmcnt(0)" ::: "memory");                         \
    __builtin_amdgcn_sched_barrier(0);                                         \
    __builtin_amdgcn_s_setprio(1);                                             \
    _Pragma("unroll")                                                          \
    for (int mf = 0; mf < 4; mf++)                                             \
      _Pragma("unroll")                                                        \
      for (int nf = 0; nf < 4; nf++)                                           \
        acc[4 + mf][nf] = mfma16(a2_[mf], b_[nf], acc[4 + mf][nf]);            \
    __builtin_amdgcn_s_setprio(0);                                             \
    __builtin_amdgcn_sched_barrier(0);                                         \
    asm volatile(WAITASM ::: "memory");                                        \
    __builtin_amdgcn_s_barrier();                                              \
    FENCE();                                                                   \
  } while (0)

template <int KT>
__device__ __forceinline__ void core256(const u16* __restrict__ Ag,
                                        const u16* __restrict__ Bg,
                                        u16* L, f32x4 acc[8][4])
{
  constexpr int NKT = KT / 32;
  const int tid  = threadIdx.x;
  const int lane = tid & 63;
  const int wv   = tid >> 6;            // 0..7
  const int wr = wv >> 2, wc = wv & 3;

  // staging source precompute (pre-swizzled): loads 0,1 -> A; 2,3 -> B
  int grow[4], gcol[4];
#pragma unroll
  for (int i = 0; i < 4; i++) {
    int oi   = (tid + (i & 1) * 512) * 16;           // linear byte off in 16KB
    int loff = oi ^ (((oi >> 6) & 3) << 4);          // logical position
    grow[i] = loff >> 6;                             // row 0..255
    gcol[i] = (loff & 63) >> 1;                      // col element 0..31
  }
  const int W0 = wv * 1024;             // wave-uniform LDS byte base, load 0/2
  const int W1 = wv * 1024 + 8192;      // load 1/3

  // swizzled ds_read bases (byte offsets within a buffer)
  const int rowA  = wr * 128 + (lane & 15);
  const int baseA = rowA * 64 + (((lane >> 4) * 16) ^ ((rowA & 3) << 4));
  const int rowB  = wc * 64 + (lane & 15);
  const int baseB = 16384 + rowB * 64 + (((lane >> 4) * 16) ^ ((rowB & 3) << 4));

  // prologue: stage tiles 0,1,2 (12 loads/wave); wait tile 0 (vmcnt(8))
#pragma unroll
  for (int tt = 0; tt < 3; tt++) {
    STG1(tt, 0, 0); STG1(tt, 1, 0); STG1(tt, 2, 1); STG1(tt, 3, 1);
  }
  __builtin_amdgcn_sched_barrier(0);
  asm volatile("s_waitcnt vmcnt(8)" ::: "memory");
  __builtin_amdgcn_s_barrier();
  FENCE();

  for (int j = 0; j < NKT - 3; ++j)
    KBODY(j, "s_waitcnt vmcnt(8)", 1);
  KBODY(NKT - 3, "s_waitcnt vmcnt(4)", 0);
  KBODY(NKT - 2, "s_waitcnt vmcnt(0)", 0);
  KBODY(NKT - 1, "", 0);
}

// S'[q][p] = (sum_f Q[q,f] K[p,f]) * INV_SCALE  (A=Q, B=K)  256x256 tiles
__global__ __launch_bounds__(512, 2) void qk256_kernel(
    const u16* __restrict__ kb, const u16* __restrict__ qb, u16* __restrict__ S)
{
  extern __shared__ u16 L[];            // 128 KB dynamic
  int bid = blockIdx.x;                 // 512 blocks, XCD-swizzled
  int xcd = bid & 7, r = bid >> 3;      // r: 0..63
  int bh  = xcd * 4 + (r >> 4);
  int til = r & 15;
  int mt  = til >> 2, nt = til & 3;

  const u16* Ag = qb + (size_t)bh * NP * NF + (size_t)mt * 256 * NF;
  const u16* Bg = kb + (size_t)bh * NP * NF + (size_t)nt * 256 * NF;

  f32x4 acc[8][4];
#pragma unroll
  for (int a = 0; a < 8; a++)
#pragma unroll
    for (int c = 0; c < 4; c++) acc[a][c] = (f32x4){0.f, 0.f, 0.f, 0.f};

  core256<NF>(Ag, Bg, L, acc);

  const int lane = threadIdx.x & 63, wv = threadIdx.x >> 6;
  const int wr = wv >> 2, wc = wv & 3;
  u16* Sp = S + (size_t)bh * NP * NP;
#pragma unroll
  for (int mf = 0; mf < 8; mf++)
#pragma unroll
    for (int jj = 0; jj < 4; jj++) {
      int m = mt * 256 + wr * 128 + mf * 16 + (lane >> 4) * 4 + jj;   // q
#pragma unroll
      for (int nf = 0; nf < 4; nf++) {
        int n = nt * 256 + wc * 64 + nf * 16 + (lane & 15);           // p
        Sp[(size_t)m * NP + n] = f2bf(acc[mf][nf][jj] * INV_SCALE);
      }
    }
}

// Out[q][f] = sum_p A'[q,p] * Vt[f,p];  write fp32 out[b][h*32+d][q][t]
__global__ __launch_bounds__(512, 2) void av256_kernel(
    const u16* __restrict__ Ab, const u16* __restrict__ Vt, float* __restrict__ out)
{
  extern __shared__ u16 L[];            // 128 KB dynamic
  int bid = blockIdx.x;                 // 1024 blocks, XCD-swizzled
  int xcd = bid & 7, r = bid >> 3;      // r: 0..127
  int bh  = xcd * 4 + (r >> 5);
  int til = r & 31;
  int mt  = til >> 3, ntf = til & 7;

  const u16* Ag = Ab + (size_t)bh * NP * NP + (size_t)mt * 256 * NP;
  const u16* Bg = Vt + (size_t)bh * NF * NP + (size_t)ntf * 256 * NP;

  f32x4 acc[8][4];
#pragma unroll
  for (int a = 0; a < 8; a++)
#pragma unroll
    for (int c = 0; c < 4; c++) acc[a][c] = (f32x4){0.f, 0.f, 0.f, 0.f};

  core256<NP>(Ag, Bg, L, acc);

  const int lane = threadIdx.x & 63, wv = threadIdx.x >> 6;
  const int wr = wv >> 2, wc = wv & 3;
  int b = bh >> 3, h = bh & 7;
#pragma unroll
  for (int mf = 0; mf < 8; mf++)
#pragma unroll
    for (int jj = 0; jj < 4; jj++) {
      int m = mt * 256 + wr * 128 + mf * 16 + (lane >> 4) * 4 + jj;   // q
#pragma unroll
      for (int nf = 0; nf < 4; nf++) {
        int n = ntf * 256 + wc * 64 + nf * 16 + (lane & 15);          // f
        int dd = n >> 6, t = n & 63;
        out[((size_t)(b * NC + h * ND + dd) * NP + m) * NT + t] = acc[mf][nf][jj];
      }
    }
}

// Column softmax over q (rows of S'[q][p]); coalesced along p. 4-way q-split.
__global__ __launch_bounds__(256, 2) void softmax_kernel(
    const u16* __restrict__ S, u16* __restrict__ A)
{
  int cb = blockIdx.x;        // 16 blocks of 64 columns
  int bh = blockIdx.y;
  int tid = threadIdx.x;
  int c  = tid & 63;
  int qs = tid >> 6;          // 0..3
  int col = cb * 64 + c;
  const u16* Sp = S + (size_t)bh * NP * NP + col;
  float m = -1e30f, l = 0.f;
  for (int q = qs * 256; q < qs * 256 + 256; q++) {
    float v = bf2f(Sp[(size_t)q * NP]);
    float mn = fmaxf(m, v);
    l = l * __expf(m - mn) + __expf(v - mn);
    m = mn;
  }
  __shared__ float ms[4][64], ls[4][64];
  ms[qs][c] = m; ls[qs][c] = l;
  __syncthreads();
  float M = fmaxf(fmaxf(ms[0][c], ms[1][c]), fmaxf(ms[2][c], ms[3][c]));
  float L = ls[0][c] * __expf(ms[0][c] - M) + ls[1][c] * __expf(ms[1][c] - M) +
            ls[2][c] * __expf(ms[2][c] - M) + ls[3][c] * __expf(ms[3][c] - M);
  float inv = 1.f / L;
  u16* Ap = A + (size_t)bh * NP * NP + col;
  for (int q = qs * 256; q < qs * 256 + 256; q++) {
    float v = bf2f(Sp[(size_t)q * NP]);
    Ap[(size_t)q * NP] = f2bf(__expf(v - M) * inv);
  }
}

// ---------------------------------------------------------------------------
extern "C" void kernel_launch(void* const* d_in, const int* in_sizes, int n_in,
                              void* d_out, int out_size, void* d_ws, size_t ws_size,
                              hipStream_t stream)
{
  if (ws_size < 4ull * KQV_ELEMS * sizeof(u16)) return;  // need 537 MB scratch

  const float* x  = (const float*)d_in[0];
  const float* Wk = (const float*)d_in[1];
  const float* bk = (const float*)d_in[2];
  const float* Wq = (const float*)d_in[3];
  const float* bq = (const float*)d_in[4];
  const float* Wv = (const float*)d_in[5];
  const float* bv = (const float*)d_in[6];

  u16* kb = (u16*)d_ws;                    // [bh][p][f]
  u16* qb = kb + KQV_ELEMS;                // [bh][p][f]
  u16* vb = kb + 2 * KQV_ELEMS;            // [bh][p][f]
  u16* vt = kb + 3 * KQV_ELEMS;            // [bh][f][p]

  // d_out head doubles as staging: xT (134 MB) + wbf (0.4 MB) + S (67 MB).
  // All dead before av_kernel rewrites d_out in full.
  u16* xT  = (u16*)d_out;                  // [(b,pt)][c]
  u16* wbf = xT + KQV_ELEMS;               // 3 x 256 x 256
  u16* Sb  = xT + KQV_ELEMS + 262144;      // S'[bh][q][p]
  u16* Ab  = kb;                           // attn A'[bh][q][p], aliases kb

  (void)hipFuncSetAttribute((const void*)qk256_kernel,
                            hipFuncAttributeMaxDynamicSharedMemorySize, 131072);
  (void)hipFuncSetAttribute((const void*)av256_kernel,
                            hipFuncAttributeMaxDynamicSharedMemorySize, 131072);

  wcast_kernel<<<dim3(64, 3), 256, 0, stream>>>(Wk, Wq, Wv, wbf);
  xcast_kernel<<<dim3(1024, 4, 4), 256, 0, stream>>>(x, xT);
  proj_kernel<<<dim3(3072, 4), 256, 0, stream>>>(wbf, xT, bk, bq, bv, kb);
  transpose_kernel<<<dim3(32, 16, 32), 256, 0, stream>>>(vb, vt);
  qk256_kernel<<<dim3(512), 512, 131072, stream>>>(kb, qb, Sb);
  softmax_kernel<<<dim3(16, 32), 256, 0, stream>>>(Sb, Ab);
  av256_kernel<<<dim3(1024), 512, 131072, stream>>>(Ab, vt, (float*)d_out);
}